// Round 1
// baseline (7510.843 us; speedup 1.0000x reference)
//
#include <hip/hip_runtime.h>
#include <hip/hip_bf16.h>
#include <math.h>

// Problem constants
#define BB 16
#define LL 512
#define DD 512
#define DD2 1024
#define KMIX 8
#define LPAD 520          // L + 8 pad rows (4 each side) for KS=9 conv
#define GRU_KP 1056       // 1024 + 32 (bias row at k=1024, rest zero)
#define GRU_KSTEPS 33     // 1056 / 32

typedef __attribute__((ext_vector_type(8))) short short8;
typedef __attribute__((ext_vector_type(4))) float f32x4;
typedef unsigned short ushort;

__device__ __forceinline__ float bf2f(ushort u) {
  union { float f; unsigned i; } v; v.i = ((unsigned)u) << 16; return v.f;
}
__device__ __forceinline__ ushort f2bf(float f) {
  union { float f; unsigned i; } v; v.f = f;
  unsigned i = v.i;
  unsigned r = i + 0x7FFF + ((i >> 16) & 1);   // RNE
  return (ushort)(r >> 16);
}

// ---------------------------------------------------------------------------
// Elementwise prep kernels (grid-stride)
// ---------------------------------------------------------------------------
__global__ void k_zero_bf16(ushort* p, long n) {
  for (long i = blockIdx.x * 256 + threadIdx.x; i < n; i += (long)gridDim.x * 256) p[i] = 0;
}
__global__ void k_zero_f32(float* p, long n) {
  for (long i = blockIdx.x * 256 + threadIdx.x; i < n; i += (long)gridDim.x * 256) p[i] = 0.f;
}
// xpad[b][p][d] = p in [4,516) ? bf16(x[b][p-4][d]) : 0
__global__ void k_fill_xpad(const float* __restrict__ x, ushort* __restrict__ xp) {
  const long n = (long)BB * LPAD * DD;
  for (long i = blockIdx.x * 256 + threadIdx.x; i < n; i += (long)gridDim.x * 256) {
    int d = (int)(i & 511);
    long rest = i >> 9;
    int p = (int)(rest % LPAD);
    int b = (int)(rest / LPAD);
    float v = 0.f;
    if (p >= 4 && p < 516) v = x[((long)b * LL + (p - 4)) * DD + d];
    xp[i] = f2bf(v);
  }
}
// wpack[k][o][i] = w[o][i][k]  (conv weight -> per-segment B^T layout [N=o][K=i])
__global__ void k_pack_convw(const float* __restrict__ w, ushort* __restrict__ wp) {
  const long n = (long)DD * DD * 9;
  for (long idx = blockIdx.x * 256 + threadIdx.x; idx < n; idx += (long)gridDim.x * 256) {
    int i = (int)(idx & 511);
    int o = (int)((idx >> 9) & 511);
    int k = (int)(idx >> 18);
    wp[idx] = f2bf(w[((long)o * DD + i) * 9 + k]);
  }
}
// wihx[n][i] = w_ih[n][i], n<3072, i<512 (x-part of w_ih, B^T layout)
__global__ void k_pack_wihx(const float* __restrict__ w_ih, ushort* __restrict__ wp) {
  const long n = (long)3 * DD2 * DD;
  for (long idx = blockIdx.x * 256 + threadIdx.x; idx < n; idx += (long)gridDim.x * 256) {
    int i = (int)(idx & 511);
    int nr = (int)(idx >> 9);
    wp[idx] = f2bf(w_ih[(long)nr * 1536 + i]);
  }
}
__global__ void k_pack_bf16(const float* __restrict__ s, ushort* __restrict__ d, long n) {
  for (long i = blockIdx.x * 256 + threadIdx.x; i < n; i += (long)gridDim.x * 256) d[i] = f2bf(s[i]);
}
// GRU weights in exact B-fragment order.
// Wp[(((blk*6+s)*33+ks)*64+lane)*8 + j] = W'[k = ks*32+(lane>>4)*8+j][c = s*1024 + blk*16 + (lane&15)]
//   s in 0..2: gi_h slices  -> w_ih[(s*1024+u)][512+k], bias row = 0 (b_ih lives in gi_x)
//   s in 3..5: gh slices    -> w_hh[(s-3)*1024+u][k],   bias row (k==1024) = b_hh
__global__ void k_pack_gru(const float* __restrict__ w_ih, const float* __restrict__ w_hh,
                           const float* __restrict__ b_hh, ushort* __restrict__ wp) {
  const long n = (long)64 * 6 * GRU_KSTEPS * 64 * 8;
  for (long idx = blockIdx.x * 256 + threadIdx.x; idx < n; idx += (long)gridDim.x * 256) {
    int j = (int)(idx & 7);
    int lane = (int)((idx >> 3) & 63);
    long r9 = idx >> 9;
    int ks = (int)(r9 % GRU_KSTEPS);
    long tmp = r9 / GRU_KSTEPS;
    int s = (int)(tmp % 6);
    int blk = (int)(tmp / 6);
    int k = ks * 32 + ((lane >> 4) << 3) + j;
    int u = blk * 16 + (lane & 15);
    float v = 0.f;
    if (s < 3) {
      if (k < 1024) v = w_ih[((long)(s * DD2 + u)) * 1536 + 512 + k];
    } else {
      int nr = (s - 3) * DD2 + u;
      if (k < 1024) v = w_hh[(long)nr * DD2 + k];
      else if (k == 1024) v = b_hh[nr];
    }
    wp[idx] = f2bf(v);
  }
}

// ---------------------------------------------------------------------------
// Generic 128x128 bf16 MFMA GEMM: C[M,N] = sum_seg A_seg[M,Kseg] * Bt_seg[N,Kseg]^T
// AMAP: 0 plain rows; 1 conv (row block m0 -> xpad row (b*520 + l), lda=512)
// MODE: 0 +bias->f32 ; 1 +bias->bf16 ; 2 +bias->f32 ; 3 exp(+bias)->f32
// ---------------------------------------------------------------------------
template <int MODE, int AMAP>
__global__ __launch_bounds__(256) void gemm128(
    const ushort* __restrict__ A, int lda, long segAoff,
    const ushort* __restrict__ Bt, int ldb, long segBoff,
    int nseg, int kseg, void* __restrict__ Cout, int ldc,
    const float* __restrict__ bias) {
  __shared__ ushort As[128 * 64];
  __shared__ ushort Bs[128 * 64];
  const int tid = threadIdx.x, lane = tid & 63, w = tid >> 6;
  const int wr = w >> 1, wc = w & 1;  // 2x2 wave grid, 64x64 C per wave
  const int m0 = blockIdx.y * 128, n0 = blockIdx.x * 128;

  const ushort* Abase;
  if (AMAP == 1) {
    int b = m0 >> 9, l = m0 & 511;
    Abase = A + ((long)(b * LPAD + l)) * DD;
  } else {
    Abase = A + (long)m0 * lda;
  }
  const ushort* Bbase = Bt + (long)n0 * ldb;

  f32x4 acc[4][4];
#pragma unroll
  for (int i = 0; i < 4; i++)
#pragma unroll
    for (int j = 0; j < 4; j++) acc[i][j] = {0.f, 0.f, 0.f, 0.f};

  for (int seg = 0; seg < nseg; ++seg) {
    const ushort* Aseg = Abase + (long)seg * segAoff;
    const ushort* Bseg = Bbase + (long)seg * segBoff;
    for (int k0 = 0; k0 < kseg; k0 += 64) {
      // stage 128x64 A and B tiles; XOR chunk swizzle (chunk ^= row&7) kills the
      // 16-way ds_read bank conflict (G4). 1024 16B chunks per matrix, 4/thread.
#pragma unroll
      for (int it = 0; it < 4; ++it) {
        int chunk = it * 256 + tid;
        int r = chunk >> 3, cc = chunk & 7;
        int sc = cc ^ (r & 7);
        *(short8*)&As[(size_t)chunk * 8] = *(const short8*)(Aseg + (long)r * lda + k0 + sc * 8);
        *(short8*)&Bs[(size_t)chunk * 8] = *(const short8*)(Bseg + (long)r * ldb + k0 + sc * 8);
      }
      __syncthreads();
#pragma unroll
      for (int kk = 0; kk < 2; ++kk) {
        short8 af[4], bfv[4];
#pragma unroll
        for (int m = 0; m < 4; m++) {
          int row = wr * 64 + m * 16 + (lane & 15);
          int ch = (kk * 4 + (lane >> 4)) ^ (row & 7);
          af[m] = *(const short8*)&As[(size_t)(row * 8 + ch) * 8];
        }
#pragma unroll
        for (int nn = 0; nn < 4; nn++) {
          int row = wc * 64 + nn * 16 + (lane & 15);
          int ch = (kk * 4 + (lane >> 4)) ^ (row & 7);
          bfv[nn] = *(const short8*)&Bs[(size_t)(row * 8 + ch) * 8];
        }
#pragma unroll
        for (int m = 0; m < 4; m++)
#pragma unroll
          for (int nn = 0; nn < 4; nn++)
            acc[m][nn] = __builtin_amdgcn_mfma_f32_16x16x32_bf16(af[m], bfv[nn], acc[m][nn], 0, 0, 0);
      }
      __syncthreads();
    }
  }
  // epilogue: C layout col=lane&15, row=(lane>>4)*4+j (m89-verified)
  float bvals[4];
#pragma unroll
  for (int nn = 0; nn < 4; nn++) {
    int c = n0 + wc * 64 + nn * 16 + (lane & 15);
    bvals[nn] = bias[c];
  }
#pragma unroll
  for (int m = 0; m < 4; m++) {
    int rbase = m0 + wr * 64 + m * 16 + ((lane >> 4) << 2);
#pragma unroll
    for (int nn = 0; nn < 4; nn++) {
      int c = n0 + wc * 64 + nn * 16 + (lane & 15);
#pragma unroll
      for (int j = 0; j < 4; j++) {
        float v = acc[m][nn][j] + bvals[nn];
        long off = (long)(rbase + j) * ldc + c;
        if (MODE == 0) ((float*)Cout)[off] = v;
        else if (MODE == 1) ((ushort*)Cout)[off] = f2bf(v);
        else if (MODE == 2) ((float*)Cout)[off] = v;
        else ((float*)Cout)[off] = expf(v);
      }
    }
  }
}

// ---------------------------------------------------------------------------
// LayerNorm(D=512) + ReLU, one 256-thread block per row.
// DSTPAD=1: write bf16 into xpad row (b*520 + l + 4); DSTPAD=0: plain [r][d].
// ---------------------------------------------------------------------------
template <int DSTPAD>
__global__ __launch_bounds__(256) void ln_relu(
    const float* __restrict__ y, const float* __restrict__ g,
    const float* __restrict__ be, ushort* __restrict__ dst) {
  const int r = blockIdx.x, tid = threadIdx.x;
  float v0 = y[(long)r * DD + tid];
  float v1 = y[(long)r * DD + 256 + tid];
  float s = v0 + v1, sq = v0 * v0 + v1 * v1;
#pragma unroll
  for (int o = 32; o; o >>= 1) { s += __shfl_down(s, o); sq += __shfl_down(sq, o); }
  __shared__ float red[8];
  int w = tid >> 6, lane = tid & 63;
  if (lane == 0) { red[w] = s; red[4 + w] = sq; }
  __syncthreads();
  if (tid == 0) {
    float ts = 0.f, tq = 0.f;
#pragma unroll
    for (int i = 0; i < 4; i++) { ts += red[i]; tq += red[4 + i]; }
    red[0] = ts; red[1] = tq;
  }
  __syncthreads();
  float mean = red[0] * (1.f / 512.f);
  float var = red[1] * (1.f / 512.f) - mean * mean;
  float rs = rsqrtf(var + 1e-5f);
  long dbase;
  if (DSTPAD) { int b = r >> 9, l = r & 511; dbase = ((long)(b * LPAD + l + 4)) * DD; }
  else dbase = (long)r * DD;
  float o0 = fmaxf(0.f, (v0 - mean) * rs * g[tid] + be[tid]);
  float o1 = fmaxf(0.f, (v1 - mean) * rs * g[tid + 256] + be[tid + 256]);
  dst[dbase + tid] = f2bf(o0);
  dst[dbase + 256 + tid] = f2bf(o1);
}

// ---------------------------------------------------------------------------
// One GRU time step. 64 blocks x 4 waves. Block blk owns units [blk*16, blk*16+16).
// Per block: C[16 batch, 6 slices x 16 units] = h_aug[16,1056] @ W'[1056, ...]
// (bias row baked at k=1024). Waves split the 33 ksteps, LDS-reduce, wave0 gates.
// ---------------------------------------------------------------------------
__global__ __launch_bounds__(256) void gru_step(
    const float* __restrict__ h_in, float* __restrict__ h_out,
    const ushort* __restrict__ gix, const ushort* __restrict__ Wp,
    ushort* __restrict__ h_seq, int t) {
  __shared__ ushort Alds[GRU_KSTEPS * 64 * 8];   // 33792 B, frag-ordered
  __shared__ float red[3 * 6 * 256];             // 18432 B
  const int tid = threadIdx.x, lane = tid & 63, w = tid >> 6, blk = blockIdx.x;

  // Stage A = [h (bf16) | 1.0 | zeros] in fragment order: chunk=(ks,lane), 8 bf16.
  for (int chunk = tid; chunk < GRU_KSTEPS * 64; chunk += 256) {
    int ks = chunk >> 6, ln = chunk & 63;
    int b = ln & 15, kb = ks * 32 + ((ln >> 4) << 3);
    short8 v;
#pragma unroll
    for (int j = 0; j < 8; j++) {
      int k = kb + j;
      float f = (k < 1024) ? h_in[b * DD2 + k] : (k == 1024 ? 1.f : 0.f);
      v[j] = (short)f2bf(f);
    }
    *(short8*)&Alds[(size_t)chunk * 8] = v;
  }
  __syncthreads();

  f32x4 acc[6];
#pragma unroll
  for (int s = 0; s < 6; s++) acc[s] = {0.f, 0.f, 0.f, 0.f};
  const int ks0 = (w == 0) ? 0 : (9 + 8 * (w - 1));
  const int ks1 = (w == 0) ? 9 : (9 + 8 * w);
  for (int ks = ks0; ks < ks1; ++ks) {
    short8 a = *(const short8*)&Alds[(size_t)(ks * 64 + lane) * 8];
#pragma unroll
    for (int s = 0; s < 6; s++) {
      const ushort* bp = Wp + ((((long)(blk * 6 + s)) * GRU_KSTEPS + ks) * 64 + lane) * 8;
      short8 bfr = *(const short8*)bp;
      acc[s] = __builtin_amdgcn_mfma_f32_16x16x32_bf16(a, bfr, acc[s], 0, 0, 0);
    }
  }
  __syncthreads();
  if (w) {
#pragma unroll
    for (int s = 0; s < 6; s++)
#pragma unroll
      for (int j = 0; j < 4; j++) red[(((w - 1) * 6 + s) << 8) + lane * 4 + j] = acc[s][j];
  }
  __syncthreads();
  if (w == 0) {
#pragma unroll
    for (int s = 0; s < 6; s++)
      for (int wv = 0; wv < 3; wv++)
#pragma unroll
        for (int j = 0; j < 4; j++) acc[s][j] += red[((wv * 6 + s) << 8) + lane * 4 + j];
    const int u = blk * 16 + (lane & 15);
#pragma unroll
    for (int j = 0; j < 4; j++) {
      int b = ((lane >> 4) << 2) + j;
      long gr = ((long)b * LL + t) * 3072;
      float gx_r = bf2f(gix[gr + u]);
      float gx_z = bf2f(gix[gr + DD2 + u]);
      float gx_n = bf2f(gix[gr + 2 * DD2 + u]);
      float hold = h_in[b * DD2 + u];
      float rg = 1.f / (1.f + expf(-(gx_r + acc[0][j] + acc[3][j])));
      float zg = 1.f / (1.f + expf(-(gx_z + acc[1][j] + acc[4][j])));
      float ng = tanhf(gx_n + acc[2][j] + rg * acc[5][j]);
      float hn = (1.f - zg) * ng + zg * hold;
      h_out[b * DD2 + u] = hn;
      h_seq[((long)b * LL + t) * DD2 + u] = f2bf(hn);
    }
  }
}

// ---------------------------------------------------------------------------
// Mixture-weight head: logits[r][k] = h[r] . ww[k] + wb[k], softmax over K=8.
// One wave per row, 4 rows per block.
// ---------------------------------------------------------------------------
__global__ __launch_bounds__(256) void w_head(
    const ushort* __restrict__ h_seq, const float* __restrict__ ww,
    const float* __restrict__ wb, float* __restrict__ out) {
  const int tid = threadIdx.x, lane = tid & 63, w = tid >> 6;
  const long r = (long)blockIdx.x * 4 + w;
  float s[KMIX];
#pragma unroll
  for (int k = 0; k < KMIX; k++) s[k] = 0.f;
  for (int u = lane; u < DD2; u += 64) {
    float hv = bf2f(h_seq[r * DD2 + u]);
#pragma unroll
    for (int k = 0; k < KMIX; k++) s[k] += hv * ww[(long)k * DD2 + u];
  }
#pragma unroll
  for (int k = 0; k < KMIX; k++)
#pragma unroll
    for (int o = 32; o; o >>= 1) s[k] += __shfl_xor(s[k], o);
#pragma unroll
  for (int k = 0; k < KMIX; k++) s[k] += wb[k];
  float m = s[0];
#pragma unroll
  for (int k = 1; k < KMIX; k++) m = fmaxf(m, s[k]);
  float esum = 0.f;
#pragma unroll
  for (int k = 0; k < KMIX; k++) { s[k] = expf(s[k] - m); esum += s[k]; }
  float mine = 0.f;
#pragma unroll
  for (int k = 0; k < KMIX; k++) if (lane == k) mine = s[k];
  if (lane < KMIX) out[r * KMIX + lane] = mine / esum;
}

// ---------------------------------------------------------------------------
extern "C" void kernel_launch(void* const* d_in, const int* in_sizes, int n_in,
                              void* d_out, int out_size, void* d_ws, size_t ws_size,
                              hipStream_t stream) {
  const float* h_text     = (const float*)d_in[0];
  const float* conv1_w    = (const float*)d_in[1];
  const float* conv1_b    = (const float*)d_in[2];
  const float* ln1_g      = (const float*)d_in[3];
  const float* ln1_b      = (const float*)d_in[4];
  const float* conv2_w    = (const float*)d_in[5];
  const float* conv2_b    = (const float*)d_in[6];
  const float* ln2_g      = (const float*)d_in[7];
  const float* ln2_b      = (const float*)d_in[8];
  const float* w_ih       = (const float*)d_in[9];
  const float* w_hh       = (const float*)d_in[10];
  const float* b_ih       = (const float*)d_in[11];
  const float* b_hh       = (const float*)d_in[12];
  const float* mdn_w_w    = (const float*)d_in[13];
  const float* mdn_w_b    = (const float*)d_in[14];
  const float* mdn_sig_w  = (const float*)d_in[15];
  const float* mdn_sig_b  = (const float*)d_in[16];
  const float* mdn_mu_w   = (const float*)d_in[17];
  const float* mdn_mu_b   = (const float*)d_in[18];
  float* out = (float*)d_out;

  char* ws = (char*)d_ws;
  size_t off = 0;
  auto take = [&](size_t bytes) {
    void* p = ws + off;
    off += (bytes + 255) & ~(size_t)255;
    return p;
  };
  ushort* xpad1  = (ushort*)take((size_t)BB * LPAD * DD * 2);
  ushort* xpad2  = (ushort*)take((size_t)BB * LPAD * DD * 2);
  ushort* wpack1 = (ushort*)take((size_t)DD * DD * 9 * 2);
  ushort* wpack2 = (ushort*)take((size_t)DD * DD * 9 * 2);
  float*  ybuf   = (float*) take((size_t)BB * LL * DD * 4);
  ushort* x2     = (ushort*)take((size_t)BB * LL * DD * 2);
  ushort* wihx   = (ushort*)take((size_t)3 * DD2 * DD * 2);
  ushort* gix    = (ushort*)take((size_t)BB * LL * 3 * DD2 * 2);
  ushort* Wp     = (ushort*)take((size_t)64 * 6 * GRU_KSTEPS * 64 * 8 * 2);
  float*  h0     = (float*) take((size_t)BB * DD2 * 4);
  float*  h1     = (float*) take((size_t)BB * DD2 * 4);
  ushort* hseq   = (ushort*)take((size_t)BB * LL * DD2 * 2);
  ushort* mdnmu  = (ushort*)take((size_t)KMIX * DD2 * DD2 * 2);
  ushort* mdnsg  = (ushort*)take((size_t)KMIX * DD2 * DD2 * 2);

  const long sigma_off = (long)BB * LL * KMIX;                    // 65536
  const long mu_off    = sigma_off + (long)BB * LL * KMIX * DD2;  // 67174400

  // --- prep / packing ---
  k_fill_xpad<<<2048, 256, 0, stream>>>(h_text, xpad1);
  k_zero_bf16<<<2048, 256, 0, stream>>>(xpad2, (long)BB * LPAD * DD);
  k_pack_convw<<<2048, 256, 0, stream>>>(conv1_w, wpack1);
  k_pack_convw<<<2048, 256, 0, stream>>>(conv2_w, wpack2);
  k_pack_wihx<<<2048, 256, 0, stream>>>(w_ih, wihx);
  k_pack_gru<<<2048, 256, 0, stream>>>(w_ih, w_hh, b_hh, Wp);
  k_pack_bf16<<<2048, 256, 0, stream>>>(mdn_mu_w, mdnmu, (long)KMIX * DD2 * DD2);
  k_pack_bf16<<<2048, 256, 0, stream>>>(mdn_sig_w, mdnsg, (long)KMIX * DD2 * DD2);
  k_zero_f32<<<64, 256, 0, stream>>>(h0, BB * DD2);

  // --- conv block 1: y = conv(xpad1) + b ; LN+ReLU -> xpad2 ---
  gemm128<0, 1><<<dim3(4, 64), 256, 0, stream>>>(xpad1, DD, DD, wpack1, DD, (long)DD * DD, 9, DD,
                                                 ybuf, DD, conv1_b);
  ln_relu<1><<<BB * LL, 256, 0, stream>>>(ybuf, ln1_g, ln1_b, xpad2);

  // --- conv block 2 -> x2 (GRU input, plain bf16 [8192,512]) ---
  gemm128<0, 1><<<dim3(4, 64), 256, 0, stream>>>(xpad2, DD, DD, wpack2, DD, (long)DD * DD, 9, DD,
                                                 ybuf, DD, conv2_b);
  ln_relu<0><<<BB * LL, 256, 0, stream>>>(ybuf, ln2_g, ln2_b, x2);

  // --- gi_x = x2 @ w_ih[:, :512]^T + b_ih  (bf16 out, [8192, 3072]) ---
  gemm128<1, 0><<<dim3(24, 64), 256, 0, stream>>>(x2, DD, 0, wihx, DD, 0, 1, DD,
                                                  gix, 3 * DD2, b_ih);

  // --- GRU scan: 512 sequential steps ---
  for (int t = 0; t < LL; ++t) {
    const float* hin = (t & 1) ? h1 : h0;
    float* hout = (t & 1) ? h0 : h1;
    gru_step<<<64, 256, 0, stream>>>(hin, hout, gix, Wp, hseq, t);
  }

  // --- MDN heads ---
  gemm128<3, 0><<<dim3(64, 64), 256, 0, stream>>>(hseq, DD2, 0, mdnsg, DD2, 0, 1, DD2,
                                                  out + sigma_off, KMIX * DD2, mdn_sig_b);
  gemm128<2, 0><<<dim3(64, 64), 256, 0, stream>>>(hseq, DD2, 0, mdnmu, DD2, 0, 1, DD2,
                                                  out + mu_off, KMIX * DD2, mdn_mu_b);
  w_head<<<BB * LL / 4, 256, 0, stream>>>(hseq, mdn_w_w, mdn_w_b, out);
}

// Round 2
// 2208.376 us; speedup vs baseline: 3.4011x; 3.4011x over previous
//
#include <hip/hip_runtime.h>
#include <hip/hip_bf16.h>
#include <math.h>

// Problem constants
#define BB 16
#define LL 512
#define DD 512
#define DD2 1024
#define KMIX 8
#define LPAD 520          // L + 8 pad rows (4 each side) for KS=9 conv
#define GRU_KSTEPS 33     // Wp layout keeps 33 k-steps; scan uses 0..31 (bias via scalars)

typedef __attribute__((ext_vector_type(8))) short short8;
typedef __attribute__((ext_vector_type(4))) float f32x4;
typedef unsigned short ushort;

__device__ __forceinline__ float bf2f(ushort u) {
  union { float f; unsigned i; } v; v.i = ((unsigned)u) << 16; return v.f;
}
__device__ __forceinline__ ushort f2bf(float f) {
  union { float f; unsigned i; } v; v.f = f;
  unsigned i = v.i;
  unsigned r = i + 0x7FFF + ((i >> 16) & 1);   // RNE
  return (ushort)(r >> 16);
}

// ---------------------------------------------------------------------------
// Elementwise prep kernels (grid-stride)
// ---------------------------------------------------------------------------
__global__ void k_zero_bf16(ushort* p, long n) {
  for (long i = blockIdx.x * 256 + threadIdx.x; i < n; i += (long)gridDim.x * 256) p[i] = 0;
}
// xpad[b][p][d] = p in [4,516) ? bf16(x[b][p-4][d]) : 0
__global__ void k_fill_xpad(const float* __restrict__ x, ushort* __restrict__ xp) {
  const long n = (long)BB * LPAD * DD;
  for (long i = blockIdx.x * 256 + threadIdx.x; i < n; i += (long)gridDim.x * 256) {
    int d = (int)(i & 511);
    long rest = i >> 9;
    int p = (int)(rest % LPAD);
    int b = (int)(rest / LPAD);
    float v = 0.f;
    if (p >= 4 && p < 516) v = x[((long)b * LL + (p - 4)) * DD + d];
    xp[i] = f2bf(v);
  }
}
// wpack[k][o][i] = w[o][i][k]  (conv weight -> per-segment B^T layout [N=o][K=i])
__global__ void k_pack_convw(const float* __restrict__ w, ushort* __restrict__ wp) {
  const long n = (long)DD * DD * 9;
  for (long idx = blockIdx.x * 256 + threadIdx.x; idx < n; idx += (long)gridDim.x * 256) {
    int i = (int)(idx & 511);
    int o = (int)((idx >> 9) & 511);
    int k = (int)(idx >> 18);
    wp[idx] = f2bf(w[((long)o * DD + i) * 9 + k]);
  }
}
// wihx[n][i] = w_ih[n][i], n<3072, i<512 (x-part of w_ih, B^T layout)
__global__ void k_pack_wihx(const float* __restrict__ w_ih, ushort* __restrict__ wp) {
  const long n = (long)3 * DD2 * DD;
  for (long idx = blockIdx.x * 256 + threadIdx.x; idx < n; idx += (long)gridDim.x * 256) {
    int i = (int)(idx & 511);
    int nr = (int)(idx >> 9);
    wp[idx] = f2bf(w_ih[(long)nr * 1536 + i]);
  }
}
__global__ void k_pack_bf16(const float* __restrict__ s, ushort* __restrict__ d, long n) {
  for (long i = blockIdx.x * 256 + threadIdx.x; i < n; i += (long)gridDim.x * 256) d[i] = f2bf(s[i]);
}
// GRU weights in exact B-fragment order (unchanged layout from round 1; ks=32 unused now).
__global__ void k_pack_gru(const float* __restrict__ w_ih, const float* __restrict__ w_hh,
                           const float* __restrict__ b_hh, ushort* __restrict__ wp) {
  const long n = (long)64 * 6 * GRU_KSTEPS * 64 * 8;
  for (long idx = blockIdx.x * 256 + threadIdx.x; idx < n; idx += (long)gridDim.x * 256) {
    int j = (int)(idx & 7);
    int lane = (int)((idx >> 3) & 63);
    long r9 = idx >> 9;
    int ks = (int)(r9 % GRU_KSTEPS);
    long tmp = r9 / GRU_KSTEPS;
    int s = (int)(tmp % 6);
    int blk = (int)(tmp / 6);
    int k = ks * 32 + ((lane >> 4) << 3) + j;
    int u = blk * 16 + (lane & 15);
    float v = 0.f;
    if (s < 3) {
      if (k < 1024) v = w_ih[((long)(s * DD2 + u)) * 1536 + 512 + k];
    } else {
      int nr = (s - 3) * DD2 + u;
      if (k < 1024) v = w_hh[(long)nr * DD2 + k];
      else if (k == 1024) v = b_hh[nr];
    }
    wp[idx] = f2bf(v);
  }
}
// Zero hbuf[0] (h0 = 0, frag order) and the barrier counter.
__global__ void k_init_hbuf(ushort* hb, unsigned* bar) {
  int i = blockIdx.x * 256 + threadIdx.x;
  if (i == 0) __hip_atomic_store(bar, 0u, __ATOMIC_RELAXED, __HIP_MEMORY_SCOPE_AGENT);
  if (i < 16384) hb[i] = 0;
}

// ---------------------------------------------------------------------------
// Generic 128x128 bf16 MFMA GEMM (unchanged from round 1).
// ---------------------------------------------------------------------------
template <int MODE, int AMAP>
__global__ __launch_bounds__(256) void gemm128(
    const ushort* __restrict__ A, int lda, long segAoff,
    const ushort* __restrict__ Bt, int ldb, long segBoff,
    int nseg, int kseg, void* __restrict__ Cout, int ldc,
    const float* __restrict__ bias) {
  __shared__ ushort As[128 * 64];
  __shared__ ushort Bs[128 * 64];
  const int tid = threadIdx.x, lane = tid & 63, w = tid >> 6;
  const int wr = w >> 1, wc = w & 1;
  const int m0 = blockIdx.y * 128, n0 = blockIdx.x * 128;

  const ushort* Abase;
  if (AMAP == 1) {
    int b = m0 >> 9, l = m0 & 511;
    Abase = A + ((long)(b * LPAD + l)) * DD;
  } else {
    Abase = A + (long)m0 * lda;
  }
  const ushort* Bbase = Bt + (long)n0 * ldb;

  f32x4 acc[4][4];
#pragma unroll
  for (int i = 0; i < 4; i++)
#pragma unroll
    for (int j = 0; j < 4; j++) acc[i][j] = {0.f, 0.f, 0.f, 0.f};

  for (int seg = 0; seg < nseg; ++seg) {
    const ushort* Aseg = Abase + (long)seg * segAoff;
    const ushort* Bseg = Bbase + (long)seg * segBoff;
    for (int k0 = 0; k0 < kseg; k0 += 64) {
#pragma unroll
      for (int it = 0; it < 4; ++it) {
        int chunk = it * 256 + tid;
        int r = chunk >> 3, cc = chunk & 7;
        int sc = cc ^ (r & 7);
        *(short8*)&As[(size_t)chunk * 8] = *(const short8*)(Aseg + (long)r * lda + k0 + sc * 8);
        *(short8*)&Bs[(size_t)chunk * 8] = *(const short8*)(Bseg + (long)r * ldb + k0 + sc * 8);
      }
      __syncthreads();
#pragma unroll
      for (int kk = 0; kk < 2; ++kk) {
        short8 af[4], bfv[4];
#pragma unroll
        for (int m = 0; m < 4; m++) {
          int row = wr * 64 + m * 16 + (lane & 15);
          int ch = (kk * 4 + (lane >> 4)) ^ (row & 7);
          af[m] = *(const short8*)&As[(size_t)(row * 8 + ch) * 8];
        }
#pragma unroll
        for (int nn = 0; nn < 4; nn++) {
          int row = wc * 64 + nn * 16 + (lane & 15);
          int ch = (kk * 4 + (lane >> 4)) ^ (row & 7);
          bfv[nn] = *(const short8*)&Bs[(size_t)(row * 8 + ch) * 8];
        }
#pragma unroll
        for (int m = 0; m < 4; m++)
#pragma unroll
          for (int nn = 0; nn < 4; nn++)
            acc[m][nn] = __builtin_amdgcn_mfma_f32_16x16x32_bf16(af[m], bfv[nn], acc[m][nn], 0, 0, 0);
      }
      __syncthreads();
    }
  }
  float bvals[4];
#pragma unroll
  for (int nn = 0; nn < 4; nn++) {
    int c = n0 + wc * 64 + nn * 16 + (lane & 15);
    bvals[nn] = bias[c];
  }
#pragma unroll
  for (int m = 0; m < 4; m++) {
    int rbase = m0 + wr * 64 + m * 16 + ((lane >> 4) << 2);
#pragma unroll
    for (int nn = 0; nn < 4; nn++) {
      int c = n0 + wc * 64 + nn * 16 + (lane & 15);
#pragma unroll
      for (int j = 0; j < 4; j++) {
        float v = acc[m][nn][j] + bvals[nn];
        long off = (long)(rbase + j) * ldc + c;
        if (MODE == 0) ((float*)Cout)[off] = v;
        else if (MODE == 1) ((ushort*)Cout)[off] = f2bf(v);
        else if (MODE == 2) ((float*)Cout)[off] = v;
        else ((float*)Cout)[off] = expf(v);
      }
    }
  }
}

// ---------------------------------------------------------------------------
// LayerNorm(D=512) + ReLU (unchanged).
// ---------------------------------------------------------------------------
template <int DSTPAD>
__global__ __launch_bounds__(256) void ln_relu(
    const float* __restrict__ y, const float* __restrict__ g,
    const float* __restrict__ be, ushort* __restrict__ dst) {
  const int r = blockIdx.x, tid = threadIdx.x;
  float v0 = y[(long)r * DD + tid];
  float v1 = y[(long)r * DD + 256 + tid];
  float s = v0 + v1, sq = v0 * v0 + v1 * v1;
#pragma unroll
  for (int o = 32; o; o >>= 1) { s += __shfl_down(s, o); sq += __shfl_down(sq, o); }
  __shared__ float red[8];
  int w = tid >> 6, lane = tid & 63;
  if (lane == 0) { red[w] = s; red[4 + w] = sq; }
  __syncthreads();
  if (tid == 0) {
    float ts = 0.f, tq = 0.f;
#pragma unroll
    for (int i = 0; i < 4; i++) { ts += red[i]; tq += red[4 + i]; }
    red[0] = ts; red[1] = tq;
  }
  __syncthreads();
  float mean = red[0] * (1.f / 512.f);
  float var = red[1] * (1.f / 512.f) - mean * mean;
  float rs = rsqrtf(var + 1e-5f);
  long dbase;
  if (DSTPAD) { int b = r >> 9, l = r & 511; dbase = ((long)(b * LPAD + l + 4)) * DD; }
  else dbase = (long)r * DD;
  float o0 = fmaxf(0.f, (v0 - mean) * rs * g[tid] + be[tid]);
  float o1 = fmaxf(0.f, (v1 - mean) * rs * g[tid + 256] + be[tid + 256]);
  dst[dbase + tid] = f2bf(o0);
  dst[dbase + 256 + tid] = f2bf(o1);
}

// ---------------------------------------------------------------------------
// Persistent GRU scan. 64 blocks x 256 threads, all co-resident.
// Step t: read hbuf[t] (frag order, write-once, agent-scope loads),
// MFMA h@W' split over 4 waves (stride-4 k-steps), LDS reduce (transposed,
// conflict-free), all 256 threads compute gates for their fixed (u,b),
// write hbuf[t+1] + h_seq, then device barrier (agent atomic counter).
// h_old stays f32 in a register (same thread owns (u,b) every step).
// ---------------------------------------------------------------------------
__global__ __launch_bounds__(256, 1) void gru_scan(
    const ushort* __restrict__ Wp, const ushort* __restrict__ gix,
    const float* __restrict__ b_hh,
    ushort* __restrict__ hbuf, ushort* __restrict__ h_seq,
    unsigned* __restrict__ bar) {
  __shared__ float red[4 * 6 * 256];  // 24 KB
  const int tid = threadIdx.x, lane = tid & 63, w = tid >> 6, blk = blockIdx.x;
  const int j_c = tid >> 6;
  const int u_local = lane & 15;
  const int b = ((lane >> 4) << 2) + j_c;        // gate-phase batch
  const int u = (blk << 4) + u_local;            // gate-phase unit
  // frag position of (u,b) in next step's A buffer: k=u
  const int lanep = ((blk & 1) * 2 + (u_local >> 3)) * 16 + b;
  const long hout_off = ((long)(blk >> 1) * 64 + lanep) * 8 + (u_local & 7);
  const ushort* wpw = Wp + (long)blk * 6 * GRU_KSTEPS * 512 + (long)lane * 8;
  const float bhr = b_hh[u], bhz = b_hh[DD2 + u], bhn = b_hh[2 * DD2 + u];
  float hold = 0.f;

  // Preload slices 0..2 (gi_h) into registers: 96 VGPRs, halves per-step L2 reads.
  short8 wreg0[8], wreg1[8], wreg2[8];
#pragma unroll
  for (int i = 0; i < 8; ++i) {
    const int ks = i * 4 + w;
    wreg0[i] = *(const short8*)(wpw + (long)(0 * GRU_KSTEPS + ks) * 512);
    wreg1[i] = *(const short8*)(wpw + (long)(1 * GRU_KSTEPS + ks) * 512);
    wreg2[i] = *(const short8*)(wpw + (long)(2 * GRU_KSTEPS + ks) * 512);
  }

  for (int t = 0; t < LL; ++t) {
    const ushort* hb = hbuf + ((long)t << 14);
    // gate-input prefetch (independent of the barrier)
    const long gr = ((long)b * LL + t) * 3072 + u;
    const float gx_r = bf2f(gix[gr]);
    const float gx_z = bf2f(gix[gr + DD2]);
    const float gx_n = bf2f(gix[gr + 2 * DD2]);

    f32x4 acc0 = {0.f,0.f,0.f,0.f}, acc1 = acc0, acc2 = acc0,
          acc3 = acc0, acc4 = acc0, acc5 = acc0;
#pragma unroll
    for (int i = 0; i < 8; ++i) {
      const int ks = i * 4 + w;
      unsigned long long* ap = (unsigned long long*)(hb + (((long)ks * 64 + lane) << 3));
      union { unsigned long long q[2]; short8 v; } cv;
      cv.q[0] = __hip_atomic_load(ap,     __ATOMIC_RELAXED, __HIP_MEMORY_SCOPE_AGENT);
      cv.q[1] = __hip_atomic_load(ap + 1, __ATOMIC_RELAXED, __HIP_MEMORY_SCOPE_AGENT);
      short8 b3 = *(const short8*)(wpw + (long)(3 * GRU_KSTEPS + ks) * 512);
      short8 b4 = *(const short8*)(wpw + (long)(4 * GRU_KSTEPS + ks) * 512);
      short8 b5 = *(const short8*)(wpw + (long)(5 * GRU_KSTEPS + ks) * 512);
      acc0 = __builtin_amdgcn_mfma_f32_16x16x32_bf16(cv.v, wreg0[i], acc0, 0, 0, 0);
      acc1 = __builtin_amdgcn_mfma_f32_16x16x32_bf16(cv.v, wreg1[i], acc1, 0, 0, 0);
      acc2 = __builtin_amdgcn_mfma_f32_16x16x32_bf16(cv.v, wreg2[i], acc2, 0, 0, 0);
      acc3 = __builtin_amdgcn_mfma_f32_16x16x32_bf16(cv.v, b3, acc3, 0, 0, 0);
      acc4 = __builtin_amdgcn_mfma_f32_16x16x32_bf16(cv.v, b4, acc4, 0, 0, 0);
      acc5 = __builtin_amdgcn_mfma_f32_16x16x32_bf16(cv.v, b5, acc5, 0, 0, 0);
    }
    // Cross-wave reduce, transposed layout (writes: const+lane; reads: const+lane).
#pragma unroll
    for (int j = 0; j < 4; ++j) {
      red[((w * 6 + 0) << 8) + (j << 6) + lane] = acc0[j];
      red[((w * 6 + 1) << 8) + (j << 6) + lane] = acc1[j];
      red[((w * 6 + 2) << 8) + (j << 6) + lane] = acc2[j];
      red[((w * 6 + 3) << 8) + (j << 6) + lane] = acc3[j];
      red[((w * 6 + 4) << 8) + (j << 6) + lane] = acc4[j];
      red[((w * 6 + 5) << 8) + (j << 6) + lane] = acc5[j];
    }
    __syncthreads();
    float v0 = 0.f, v1 = 0.f, v2 = 0.f, v3 = 0.f, v4 = 0.f, v5 = 0.f;
#pragma unroll
    for (int wv = 0; wv < 4; ++wv) {
      const int base = ((wv * 6) << 8) + (j_c << 6) + lane;
      v0 += red[base];
      v1 += red[base + 256];
      v2 += red[base + 512];
      v3 += red[base + 768];
      v4 += red[base + 1024];
      v5 += red[base + 1280];
    }
    // gates (b_hh folded in as scalars; n-gate bias inside r*(.) per torch GRUCell)
    const float rg = 1.f / (1.f + __expf(-(gx_r + v0 + v3 + bhr)));
    const float zg = 1.f / (1.f + __expf(-(gx_z + v1 + v4 + bhz)));
    const float nx = gx_n + v2 + rg * (v5 + bhn);
    const float ng = 1.f - 2.f / (__expf(2.f * nx) + 1.f);
    const float hn = (1.f - zg) * ng + zg * hold;
    hold = hn;
    const ushort h16 = f2bf(hn);
    h_seq[((long)b * LL + t) * DD2 + u] = h16;
    if (t < LL - 1) {
      // write-through to coherence point (Infinity Cache) — visible to all XCDs
      __hip_atomic_store(hbuf + (((long)(t + 1)) << 14) + hout_off, h16,
                         __ATOMIC_RELAXED, __HIP_MEMORY_SCOPE_AGENT);
      __syncthreads();  // drains vmcnt(0): all h stores complete at L3 before arrive
      if (tid == 0) {
        __hip_atomic_fetch_add(bar, 1u, __ATOMIC_RELAXED, __HIP_MEMORY_SCOPE_AGENT);
        const unsigned tgt = 64u * (unsigned)(t + 1);
        while (__hip_atomic_load(bar, __ATOMIC_RELAXED, __HIP_MEMORY_SCOPE_AGENT) < tgt)
          __builtin_amdgcn_s_sleep(1);
      }
      __syncthreads();
    }
  }
}

// ---------------------------------------------------------------------------
// Mixture-weight head (unchanged).
// ---------------------------------------------------------------------------
__global__ __launch_bounds__(256) void w_head(
    const ushort* __restrict__ h_seq, const float* __restrict__ ww,
    const float* __restrict__ wb, float* __restrict__ out) {
  const int tid = threadIdx.x, lane = tid & 63, w = tid >> 6;
  const long r = (long)blockIdx.x * 4 + w;
  float s[KMIX];
#pragma unroll
  for (int k = 0; k < KMIX; k++) s[k] = 0.f;
  for (int u = lane; u < DD2; u += 64) {
    float hv = bf2f(h_seq[r * DD2 + u]);
#pragma unroll
    for (int k = 0; k < KMIX; k++) s[k] += hv * ww[(long)k * DD2 + u];
  }
#pragma unroll
  for (int k = 0; k < KMIX; k++)
#pragma unroll
    for (int o = 32; o; o >>= 1) s[k] += __shfl_xor(s[k], o);
#pragma unroll
  for (int k = 0; k < KMIX; k++) s[k] += wb[k];
  float m = s[0];
#pragma unroll
  for (int k = 1; k < KMIX; k++) m = fmaxf(m, s[k]);
  float esum = 0.f;
#pragma unroll
  for (int k = 0; k < KMIX; k++) { s[k] = expf(s[k] - m); esum += s[k]; }
  float mine = 0.f;
#pragma unroll
  for (int k = 0; k < KMIX; k++) if (lane == k) mine = s[k];
  if (lane < KMIX) out[r * KMIX + lane] = mine / esum;
}

// ---------------------------------------------------------------------------
extern "C" void kernel_launch(void* const* d_in, const int* in_sizes, int n_in,
                              void* d_out, int out_size, void* d_ws, size_t ws_size,
                              hipStream_t stream) {
  const float* h_text     = (const float*)d_in[0];
  const float* conv1_w    = (const float*)d_in[1];
  const float* conv1_b    = (const float*)d_in[2];
  const float* ln1_g      = (const float*)d_in[3];
  const float* ln1_b      = (const float*)d_in[4];
  const float* conv2_w    = (const float*)d_in[5];
  const float* conv2_b    = (const float*)d_in[6];
  const float* ln2_g      = (const float*)d_in[7];
  const float* ln2_b      = (const float*)d_in[8];
  const float* w_ih       = (const float*)d_in[9];
  const float* w_hh       = (const float*)d_in[10];
  const float* b_ih       = (const float*)d_in[11];
  const float* b_hh       = (const float*)d_in[12];
  const float* mdn_w_w    = (const float*)d_in[13];
  const float* mdn_w_b    = (const float*)d_in[14];
  const float* mdn_sig_w  = (const float*)d_in[15];
  const float* mdn_sig_b  = (const float*)d_in[16];
  const float* mdn_mu_w   = (const float*)d_in[17];
  const float* mdn_mu_b   = (const float*)d_in[18];
  float* out = (float*)d_out;

  char* ws = (char*)d_ws;
  size_t off = 0;
  auto take = [&](size_t bytes) {
    void* p = ws + off;
    off += (bytes + 255) & ~(size_t)255;
    return p;
  };
  ushort* xpad1  = (ushort*)take((size_t)BB * LPAD * DD * 2);
  ushort* xpad2  = (ushort*)take((size_t)BB * LPAD * DD * 2);
  ushort* wpack1 = (ushort*)take((size_t)DD * DD * 9 * 2);
  ushort* wpack2 = (ushort*)take((size_t)DD * DD * 9 * 2);
  float*  ybuf   = (float*) take((size_t)BB * LL * DD * 4);
  ushort* x2     = (ushort*)take((size_t)BB * LL * DD * 2);
  ushort* wihx   = (ushort*)take((size_t)3 * DD2 * DD * 2);
  ushort* gix    = (ushort*)take((size_t)BB * LL * 3 * DD2 * 2);
  ushort* Wp     = (ushort*)take((size_t)64 * 6 * GRU_KSTEPS * 64 * 8 * 2);
  ushort* hseq   = (ushort*)take((size_t)BB * LL * DD2 * 2);
  ushort* mdnmu  = (ushort*)take((size_t)KMIX * DD2 * DD2 * 2);
  ushort* mdnsg  = (ushort*)take((size_t)KMIX * DD2 * DD2 * 2);
  ushort* hbuf   = (ushort*)take((size_t)512 * 16384 * 2);   // 512 write-once frag buffers
  unsigned* bar  = (unsigned*)take(256);

  const long sigma_off = (long)BB * LL * KMIX;                    // 65536
  const long mu_off    = sigma_off + (long)BB * LL * KMIX * DD2;  // 67174400

  // --- prep / packing ---
  k_fill_xpad<<<2048, 256, 0, stream>>>(h_text, xpad1);
  k_zero_bf16<<<2048, 256, 0, stream>>>(xpad2, (long)BB * LPAD * DD);
  k_pack_convw<<<2048, 256, 0, stream>>>(conv1_w, wpack1);
  k_pack_convw<<<2048, 256, 0, stream>>>(conv2_w, wpack2);
  k_pack_wihx<<<2048, 256, 0, stream>>>(w_ih, wihx);
  k_pack_gru<<<2048, 256, 0, stream>>>(w_ih, w_hh, b_hh, Wp);
  k_pack_bf16<<<2048, 256, 0, stream>>>(mdn_mu_w, mdnmu, (long)KMIX * DD2 * DD2);
  k_pack_bf16<<<2048, 256, 0, stream>>>(mdn_sig_w, mdnsg, (long)KMIX * DD2 * DD2);
  k_init_hbuf<<<64, 256, 0, stream>>>(hbuf, bar);

  // --- conv block 1: y = conv(xpad1) + b ; LN+ReLU -> xpad2 ---
  gemm128<0, 1><<<dim3(4, 64), 256, 0, stream>>>(xpad1, DD, DD, wpack1, DD, (long)DD * DD, 9, DD,
                                                 ybuf, DD, conv1_b);
  ln_relu<1><<<BB * LL, 256, 0, stream>>>(ybuf, ln1_g, ln1_b, xpad2);

  // --- conv block 2 -> x2 (GRU input, plain bf16 [8192,512]) ---
  gemm128<0, 1><<<dim3(4, 64), 256, 0, stream>>>(xpad2, DD, DD, wpack2, DD, (long)DD * DD, 9, DD,
                                                 ybuf, DD, conv2_b);
  ln_relu<0><<<BB * LL, 256, 0, stream>>>(ybuf, ln2_g, ln2_b, x2);

  // --- gi_x = x2 @ w_ih[:, :512]^T + b_ih  (bf16 out, [8192, 3072]) ---
  gemm128<1, 0><<<dim3(24, 64), 256, 0, stream>>>(x2, DD, 0, wihx, DD, 0, 1, DD,
                                                  gix, 3 * DD2, b_ih);

  // --- persistent GRU scan (single dispatch, 512 internal device barriers) ---
  gru_scan<<<64, 256, 0, stream>>>(Wp, gix, b_hh, hbuf, hseq, bar);

  // --- MDN heads ---
  gemm128<3, 0><<<dim3(64, 64), 256, 0, stream>>>(hseq, DD2, 0, mdnsg, DD2, 0, 1, DD2,
                                                  out + sigma_off, KMIX * DD2, mdn_sig_b);
  gemm128<2, 0><<<dim3(64, 64), 256, 0, stream>>>(hseq, DD2, 0, mdnmu, DD2, 0, 1, DD2,
                                                  out + mu_off, KMIX * DD2, mdn_mu_b);
  w_head<<<BB * LL / 4, 256, 0, stream>>>(hseq, mdn_w_w, mdn_w_b, out);
}

// Round 3
// 2078.306 us; speedup vs baseline: 3.6139x; 1.0626x over previous
//
#include <hip/hip_runtime.h>
#include <hip/hip_bf16.h>
#include <math.h>

// Problem constants
#define BB 16
#define LL 512
#define DD 512
#define DD2 1024
#define KMIX 8
#define LPAD 520          // L + 8 pad rows (4 each side) for KS=9 conv
#define GRU_KSTEPS 33     // Wp layout keeps 33 k-steps; scan uses 0..31 (bias via scalars)

typedef __attribute__((ext_vector_type(8))) short short8;
typedef __attribute__((ext_vector_type(4))) float f32x4;
typedef unsigned short ushort;

__device__ __forceinline__ float bf2f(ushort u) {
  union { float f; unsigned i; } v; v.i = ((unsigned)u) << 16; return v.f;
}
__device__ __forceinline__ ushort f2bf(float f) {
  union { float f; unsigned i; } v; v.f = f;
  unsigned i = v.i;
  unsigned r = i + 0x7FFF + ((i >> 16) & 1);   // RNE
  return (ushort)(r >> 16);
}

// ---------------------------------------------------------------------------
// Elementwise prep kernels (grid-stride)
// ---------------------------------------------------------------------------
__global__ void k_zero_bf16(ushort* p, long n) {
  for (long i = blockIdx.x * 256 + threadIdx.x; i < n; i += (long)gridDim.x * 256) p[i] = 0;
}
// xpad[b][p][d] = p in [4,516) ? bf16(x[b][p-4][d]) : 0
__global__ void k_fill_xpad(const float* __restrict__ x, ushort* __restrict__ xp) {
  const long n = (long)BB * LPAD * DD;
  for (long i = blockIdx.x * 256 + threadIdx.x; i < n; i += (long)gridDim.x * 256) {
    int d = (int)(i & 511);
    long rest = i >> 9;
    int p = (int)(rest % LPAD);
    int b = (int)(rest / LPAD);
    float v = 0.f;
    if (p >= 4 && p < 516) v = x[((long)b * LL + (p - 4)) * DD + d];
    xp[i] = f2bf(v);
  }
}
// wpack[k][o][i] = w[o][i][k]  (conv weight -> per-segment B^T layout [N=o][K=i])
__global__ void k_pack_convw(const float* __restrict__ w, ushort* __restrict__ wp) {
  const long n = (long)DD * DD * 9;
  for (long idx = blockIdx.x * 256 + threadIdx.x; idx < n; idx += (long)gridDim.x * 256) {
    int i = (int)(idx & 511);
    int o = (int)((idx >> 9) & 511);
    int k = (int)(idx >> 18);
    wp[idx] = f2bf(w[((long)o * DD + i) * 9 + k]);
  }
}
// wihx[n][i] = w_ih[n][i], n<3072, i<512 (x-part of w_ih, B^T layout)
__global__ void k_pack_wihx(const float* __restrict__ w_ih, ushort* __restrict__ wp) {
  const long n = (long)3 * DD2 * DD;
  for (long idx = blockIdx.x * 256 + threadIdx.x; idx < n; idx += (long)gridDim.x * 256) {
    int i = (int)(idx & 511);
    int nr = (int)(idx >> 9);
    wp[idx] = f2bf(w_ih[(long)nr * 1536 + i]);
  }
}
__global__ void k_pack_bf16(const float* __restrict__ s, ushort* __restrict__ d, long n) {
  for (long i = blockIdx.x * 256 + threadIdx.x; i < n; i += (long)gridDim.x * 256) d[i] = f2bf(s[i]);
}
// GRU weights in exact B-fragment order (layout unchanged; ks=32 unused in scan).
__global__ void k_pack_gru(const float* __restrict__ w_ih, const float* __restrict__ w_hh,
                           const float* __restrict__ b_hh, ushort* __restrict__ wp) {
  const long n = (long)64 * 6 * GRU_KSTEPS * 64 * 8;
  for (long idx = blockIdx.x * 256 + threadIdx.x; idx < n; idx += (long)gridDim.x * 256) {
    int j = (int)(idx & 7);
    int lane = (int)((idx >> 3) & 63);
    long r9 = idx >> 9;
    int ks = (int)(r9 % GRU_KSTEPS);
    long tmp = r9 / GRU_KSTEPS;
    int s = (int)(tmp % 6);
    int blk = (int)(tmp / 6);
    int k = ks * 32 + ((lane >> 4) << 3) + j;
    int u = blk * 16 + (lane & 15);
    float v = 0.f;
    if (s < 3) {
      if (k < 1024) v = w_ih[((long)(s * DD2 + u)) * 1536 + 512 + k];
    } else {
      int nr = (s - 3) * DD2 + u;
      if (k < 1024) v = w_hh[(long)nr * DD2 + k];
      else if (k == 1024) v = b_hh[nr];
    }
    wp[idx] = f2bf(v);
  }
}
// Zero hbuf[0] (h0 = 0, frag order) and the 64 padded barrier flags.
__global__ void k_init_hbuf(ushort* hb, unsigned* flags) {
  int i = blockIdx.x * 256 + threadIdx.x;
  if (i < 16384) hb[i] = 0;
  if (i < 1024) flags[i] = 0u;
}

// ---------------------------------------------------------------------------
// Generic 128x128 bf16 MFMA GEMM (unchanged).
// ---------------------------------------------------------------------------
template <int MODE, int AMAP>
__global__ __launch_bounds__(256) void gemm128(
    const ushort* __restrict__ A, int lda, long segAoff,
    const ushort* __restrict__ Bt, int ldb, long segBoff,
    int nseg, int kseg, void* __restrict__ Cout, int ldc,
    const float* __restrict__ bias) {
  __shared__ ushort As[128 * 64];
  __shared__ ushort Bs[128 * 64];
  const int tid = threadIdx.x, lane = tid & 63, w = tid >> 6;
  const int wr = w >> 1, wc = w & 1;
  const int m0 = blockIdx.y * 128, n0 = blockIdx.x * 128;

  const ushort* Abase;
  if (AMAP == 1) {
    int b = m0 >> 9, l = m0 & 511;
    Abase = A + ((long)(b * LPAD + l)) * DD;
  } else {
    Abase = A + (long)m0 * lda;
  }
  const ushort* Bbase = Bt + (long)n0 * ldb;

  f32x4 acc[4][4];
#pragma unroll
  for (int i = 0; i < 4; i++)
#pragma unroll
    for (int j = 0; j < 4; j++) acc[i][j] = {0.f, 0.f, 0.f, 0.f};

  for (int seg = 0; seg < nseg; ++seg) {
    const ushort* Aseg = Abase + (long)seg * segAoff;
    const ushort* Bseg = Bbase + (long)seg * segBoff;
    for (int k0 = 0; k0 < kseg; k0 += 64) {
#pragma unroll
      for (int it = 0; it < 4; ++it) {
        int chunk = it * 256 + tid;
        int r = chunk >> 3, cc = chunk & 7;
        int sc = cc ^ (r & 7);
        *(short8*)&As[(size_t)chunk * 8] = *(const short8*)(Aseg + (long)r * lda + k0 + sc * 8);
        *(short8*)&Bs[(size_t)chunk * 8] = *(const short8*)(Bseg + (long)r * ldb + k0 + sc * 8);
      }
      __syncthreads();
#pragma unroll
      for (int kk = 0; kk < 2; ++kk) {
        short8 af[4], bfv[4];
#pragma unroll
        for (int m = 0; m < 4; m++) {
          int row = wr * 64 + m * 16 + (lane & 15);
          int ch = (kk * 4 + (lane >> 4)) ^ (row & 7);
          af[m] = *(const short8*)&As[(size_t)(row * 8 + ch) * 8];
        }
#pragma unroll
        for (int nn = 0; nn < 4; nn++) {
          int row = wc * 64 + nn * 16 + (lane & 15);
          int ch = (kk * 4 + (lane >> 4)) ^ (row & 7);
          bfv[nn] = *(const short8*)&Bs[(size_t)(row * 8 + ch) * 8];
        }
#pragma unroll
        for (int m = 0; m < 4; m++)
#pragma unroll
          for (int nn = 0; nn < 4; nn++)
            acc[m][nn] = __builtin_amdgcn_mfma_f32_16x16x32_bf16(af[m], bfv[nn], acc[m][nn], 0, 0, 0);
      }
      __syncthreads();
    }
  }
  float bvals[4];
#pragma unroll
  for (int nn = 0; nn < 4; nn++) {
    int c = n0 + wc * 64 + nn * 16 + (lane & 15);
    bvals[nn] = bias[c];
  }
#pragma unroll
  for (int m = 0; m < 4; m++) {
    int rbase = m0 + wr * 64 + m * 16 + ((lane >> 4) << 2);
#pragma unroll
    for (int nn = 0; nn < 4; nn++) {
      int c = n0 + wc * 64 + nn * 16 + (lane & 15);
#pragma unroll
      for (int j = 0; j < 4; j++) {
        float v = acc[m][nn][j] + bvals[nn];
        long off = (long)(rbase + j) * ldc + c;
        if (MODE == 0) ((float*)Cout)[off] = v;
        else if (MODE == 1) ((ushort*)Cout)[off] = f2bf(v);
        else if (MODE == 2) ((float*)Cout)[off] = v;
        else ((float*)Cout)[off] = expf(v);
      }
    }
  }
}

// ---------------------------------------------------------------------------
// LayerNorm(D=512) + ReLU (unchanged).
// ---------------------------------------------------------------------------
template <int DSTPAD>
__global__ __launch_bounds__(256) void ln_relu(
    const float* __restrict__ y, const float* __restrict__ g,
    const float* __restrict__ be, ushort* __restrict__ dst) {
  const int r = blockIdx.x, tid = threadIdx.x;
  float v0 = y[(long)r * DD + tid];
  float v1 = y[(long)r * DD + 256 + tid];
  float s = v0 + v1, sq = v0 * v0 + v1 * v1;
#pragma unroll
  for (int o = 32; o; o >>= 1) { s += __shfl_down(s, o); sq += __shfl_down(sq, o); }
  __shared__ float red[8];
  int w = tid >> 6, lane = tid & 63;
  if (lane == 0) { red[w] = s; red[4 + w] = sq; }
  __syncthreads();
  if (tid == 0) {
    float ts = 0.f, tq = 0.f;
#pragma unroll
    for (int i = 0; i < 4; i++) { ts += red[i]; tq += red[4 + i]; }
    red[0] = ts; red[1] = tq;
  }
  __syncthreads();
  float mean = red[0] * (1.f / 512.f);
  float var = red[1] * (1.f / 512.f) - mean * mean;
  float rs = rsqrtf(var + 1e-5f);
  long dbase;
  if (DSTPAD) { int b = r >> 9, l = r & 511; dbase = ((long)(b * LPAD + l + 4)) * DD; }
  else dbase = (long)r * DD;
  float o0 = fmaxf(0.f, (v0 - mean) * rs * g[tid] + be[tid]);
  float o1 = fmaxf(0.f, (v1 - mean) * rs * g[tid + 256] + be[tid + 256]);
  dst[dbase + tid] = f2bf(o0);
  dst[dbase + 256 + tid] = f2bf(o1);
}

// ---------------------------------------------------------------------------
// Persistent GRU scan, v3. 64 blocks x 256 threads, co-resident.
// Barrier: distributed flags (no RMW). Block blk STORES flags[blk*16]=t+1
// after its h[t+1] stores drain; every block's wave 0 polls all 64 flags
// (lane l reads flags[l*16], __all(f>=t)) — one-hop, contention-free.
// gix loads are issued before the poll (overlap the wait) and non-temporal
// (don't evict the L2-resident weight slices).
// ---------------------------------------------------------------------------
__global__ __launch_bounds__(256, 1) void gru_scan(
    const ushort* __restrict__ Wp, const ushort* __restrict__ gix,
    const float* __restrict__ b_hh,
    ushort* __restrict__ hbuf, ushort* __restrict__ h_seq,
    unsigned* __restrict__ flags) {
  __shared__ float red[4 * 6 * 256];  // 24 KB
  const int tid = threadIdx.x, lane = tid & 63, w = tid >> 6, blk = blockIdx.x;
  const int j_c = w;                              // gate-phase j index = wave id
  const int u_local = lane & 15;
  const int b = ((lane >> 4) << 2) + j_c;         // gate-phase batch
  const int u = (blk << 4) + u_local;             // gate-phase unit
  // frag position of (u,b) in next step's A buffer: k=u
  const int lanep = ((blk & 1) * 2 + (u_local >> 3)) * 16 + b;
  const long hout_off = ((long)(blk >> 1) * 64 + lanep) * 8 + (u_local & 7);
  const ushort* wpw = Wp + (long)blk * 6 * GRU_KSTEPS * 512 + (long)lane * 8;
  const float bhr = b_hh[u], bhz = b_hh[DD2 + u], bhn = b_hh[2 * DD2 + u];
  float hold = 0.f;

  // Preload slices 0..2 (gi_h) into registers: 96 VGPRs.
  short8 wreg0[8], wreg1[8], wreg2[8];
#pragma unroll
  for (int i = 0; i < 8; ++i) {
    const int ks = i * 4 + w;
    wreg0[i] = *(const short8*)(wpw + (long)(0 * GRU_KSTEPS + ks) * 512);
    wreg1[i] = *(const short8*)(wpw + (long)(1 * GRU_KSTEPS + ks) * 512);
    wreg2[i] = *(const short8*)(wpw + (long)(2 * GRU_KSTEPS + ks) * 512);
  }

  for (int t = 0; t < LL; ++t) {
    // gate-input loads for step t: issue BEFORE the poll so they overlap the
    // wait; non-temporal so the 48 MB gix stream doesn't evict L2 weights.
    const long gr = ((long)b * LL + t) * 3072 + u;
    const float gx_r = bf2f(__builtin_nontemporal_load(gix + gr));
    const float gx_z = bf2f(__builtin_nontemporal_load(gix + gr + DD2));
    const float gx_n = bf2f(__builtin_nontemporal_load(gix + gr + 2 * DD2));

    // Wait for all 64 blocks to have published h[t] (t=0: hbuf[0] pre-zeroed).
    if (t > 0) {
      if (w == 0) {
        const unsigned tgt = (unsigned)t;
        while (1) {
          unsigned f = __hip_atomic_load(&flags[lane << 4], __ATOMIC_RELAXED,
                                         __HIP_MEMORY_SCOPE_AGENT);
          if (__all((int)(f >= tgt))) break;
          __builtin_amdgcn_s_sleep(1);
        }
      }
      __syncthreads();
    }

    const ushort* hb = hbuf + ((long)t << 14);
    f32x4 acc0 = {0.f,0.f,0.f,0.f}, acc1 = acc0, acc2 = acc0,
          acc3 = acc0, acc4 = acc0, acc5 = acc0;
#pragma unroll
    for (int i = 0; i < 8; ++i) {
      const int ks = i * 4 + w;
      unsigned long long* ap = (unsigned long long*)(hb + (((long)ks * 64 + lane) << 3));
      union { unsigned long long q[2]; short8 v; } cv;
      cv.q[0] = __hip_atomic_load(ap,     __ATOMIC_RELAXED, __HIP_MEMORY_SCOPE_AGENT);
      cv.q[1] = __hip_atomic_load(ap + 1, __ATOMIC_RELAXED, __HIP_MEMORY_SCOPE_AGENT);
      short8 b3 = *(const short8*)(wpw + (long)(3 * GRU_KSTEPS + ks) * 512);
      short8 b4 = *(const short8*)(wpw + (long)(4 * GRU_KSTEPS + ks) * 512);
      short8 b5 = *(const short8*)(wpw + (long)(5 * GRU_KSTEPS + ks) * 512);
      acc0 = __builtin_amdgcn_mfma_f32_16x16x32_bf16(cv.v, wreg0[i], acc0, 0, 0, 0);
      acc1 = __builtin_amdgcn_mfma_f32_16x16x32_bf16(cv.v, wreg1[i], acc1, 0, 0, 0);
      acc2 = __builtin_amdgcn_mfma_f32_16x16x32_bf16(cv.v, wreg2[i], acc2, 0, 0, 0);
      acc3 = __builtin_amdgcn_mfma_f32_16x16x32_bf16(cv.v, b3, acc3, 0, 0, 0);
      acc4 = __builtin_amdgcn_mfma_f32_16x16x32_bf16(cv.v, b4, acc4, 0, 0, 0);
      acc5 = __builtin_amdgcn_mfma_f32_16x16x32_bf16(cv.v, b5, acc5, 0, 0, 0);
    }
    // Cross-wave reduce, transposed layout (conflict-free both sides).
#pragma unroll
    for (int j = 0; j < 4; ++j) {
      red[((w * 6 + 0) << 8) + (j << 6) + lane] = acc0[j];
      red[((w * 6 + 1) << 8) + (j << 6) + lane] = acc1[j];
      red[((w * 6 + 2) << 8) + (j << 6) + lane] = acc2[j];
      red[((w * 6 + 3) << 8) + (j << 6) + lane] = acc3[j];
      red[((w * 6 + 4) << 8) + (j << 6) + lane] = acc4[j];
      red[((w * 6 + 5) << 8) + (j << 6) + lane] = acc5[j];
    }
    __syncthreads();
    float v0 = 0.f, v1 = 0.f, v2 = 0.f, v3 = 0.f, v4 = 0.f, v5 = 0.f;
#pragma unroll
    for (int wv = 0; wv < 4; ++wv) {
      const int base = ((wv * 6) << 8) + (j_c << 6) + lane;
      v0 += red[base];
      v1 += red[base + 256];
      v2 += red[base + 512];
      v3 += red[base + 768];
      v4 += red[base + 1024];
      v5 += red[base + 1280];
    }
    // gates (b_hh folded in as scalars; n-gate bias inside r*(.) per torch GRUCell)
    const float rg = 1.f / (1.f + __expf(-(gx_r + v0 + v3 + bhr)));
    const float zg = 1.f / (1.f + __expf(-(gx_z + v1 + v4 + bhz)));
    const float nx = gx_n + v2 + rg * (v5 + bhn);
    const float ng = 1.f - 2.f / (__expf(2.f * nx) + 1.f);
    const float hn = (1.f - zg) * ng + zg * hold;
    hold = hn;
    const ushort h16 = f2bf(hn);
    h_seq[((long)b * LL + t) * DD2 + u] = h16;
    if (t < LL - 1) {
      // write-through to coherence point (Infinity Cache) — visible to all XCDs
      __hip_atomic_store(hbuf + (((long)(t + 1)) << 14) + hout_off, h16,
                         __ATOMIC_RELAXED, __HIP_MEMORY_SCOPE_AGENT);
      __syncthreads();  // drains vmcnt(0): all h stores complete before the flag
      if (tid == 0)
        __hip_atomic_store(&flags[blk << 4], (unsigned)(t + 1), __ATOMIC_RELAXED,
                           __HIP_MEMORY_SCOPE_AGENT);
    }
  }
}

// ---------------------------------------------------------------------------
// Mixture-weight head (unchanged).
// ---------------------------------------------------------------------------
__global__ __launch_bounds__(256) void w_head(
    const ushort* __restrict__ h_seq, const float* __restrict__ ww,
    const float* __restrict__ wb, float* __restrict__ out) {
  const int tid = threadIdx.x, lane = tid & 63, w = tid >> 6;
  const long r = (long)blockIdx.x * 4 + w;
  float s[KMIX];
#pragma unroll
  for (int k = 0; k < KMIX; k++) s[k] = 0.f;
  for (int u = lane; u < DD2; u += 64) {
    float hv = bf2f(h_seq[r * DD2 + u]);
#pragma unroll
    for (int k = 0; k < KMIX; k++) s[k] += hv * ww[(long)k * DD2 + u];
  }
#pragma unroll
  for (int k = 0; k < KMIX; k++)
#pragma unroll
    for (int o = 32; o; o >>= 1) s[k] += __shfl_xor(s[k], o);
#pragma unroll
  for (int k = 0; k < KMIX; k++) s[k] += wb[k];
  float m = s[0];
#pragma unroll
  for (int k = 1; k < KMIX; k++) m = fmaxf(m, s[k]);
  float esum = 0.f;
#pragma unroll
  for (int k = 0; k < KMIX; k++) { s[k] = expf(s[k] - m); esum += s[k]; }
  float mine = 0.f;
#pragma unroll
  for (int k = 0; k < KMIX; k++) if (lane == k) mine = s[k];
  if (lane < KMIX) out[r * KMIX + lane] = mine / esum;
}

// ---------------------------------------------------------------------------
extern "C" void kernel_launch(void* const* d_in, const int* in_sizes, int n_in,
                              void* d_out, int out_size, void* d_ws, size_t ws_size,
                              hipStream_t stream) {
  const float* h_text     = (const float*)d_in[0];
  const float* conv1_w    = (const float*)d_in[1];
  const float* conv1_b    = (const float*)d_in[2];
  const float* ln1_g      = (const float*)d_in[3];
  const float* ln1_b      = (const float*)d_in[4];
  const float* conv2_w    = (const float*)d_in[5];
  const float* conv2_b    = (const float*)d_in[6];
  const float* ln2_g      = (const float*)d_in[7];
  const float* ln2_b      = (const float*)d_in[8];
  const float* w_ih       = (const float*)d_in[9];
  const float* w_hh       = (const float*)d_in[10];
  const float* b_ih       = (const float*)d_in[11];
  const float* b_hh       = (const float*)d_in[12];
  const float* mdn_w_w    = (const float*)d_in[13];
  const float* mdn_w_b    = (const float*)d_in[14];
  const float* mdn_sig_w  = (const float*)d_in[15];
  const float* mdn_sig_b  = (const float*)d_in[16];
  const float* mdn_mu_w   = (const float*)d_in[17];
  const float* mdn_mu_b   = (const float*)d_in[18];
  float* out = (float*)d_out;

  char* ws = (char*)d_ws;
  size_t off = 0;
  auto take = [&](size_t bytes) {
    void* p = ws + off;
    off += (bytes + 255) & ~(size_t)255;
    return p;
  };
  ushort* xpad1  = (ushort*)take((size_t)BB * LPAD * DD * 2);
  ushort* xpad2  = (ushort*)take((size_t)BB * LPAD * DD * 2);
  ushort* wpack1 = (ushort*)take((size_t)DD * DD * 9 * 2);
  ushort* wpack2 = (ushort*)take((size_t)DD * DD * 9 * 2);
  float*  ybuf   = (float*) take((size_t)BB * LL * DD * 4);
  ushort* x2     = (ushort*)take((size_t)BB * LL * DD * 2);
  ushort* wihx   = (ushort*)take((size_t)3 * DD2 * DD * 2);
  ushort* gix    = (ushort*)take((size_t)BB * LL * 3 * DD2 * 2);
  ushort* Wp     = (ushort*)take((size_t)64 * 6 * GRU_KSTEPS * 64 * 8 * 2);
  ushort* hseq   = (ushort*)take((size_t)BB * LL * DD2 * 2);
  ushort* mdnmu  = (ushort*)take((size_t)KMIX * DD2 * DD2 * 2);
  ushort* mdnsg  = (ushort*)take((size_t)KMIX * DD2 * DD2 * 2);
  ushort* hbuf   = (ushort*)take((size_t)512 * 16384 * 2);   // 512 write-once frag buffers
  unsigned* flags = (unsigned*)take(64 * 16 * 4);            // 64 flags, 64B-padded

  const long sigma_off = (long)BB * LL * KMIX;                    // 65536
  const long mu_off    = sigma_off + (long)BB * LL * KMIX * DD2;  // 67174400

  // --- prep / packing ---
  k_fill_xpad<<<2048, 256, 0, stream>>>(h_text, xpad1);
  k_zero_bf16<<<2048, 256, 0, stream>>>(xpad2, (long)BB * LPAD * DD);
  k_pack_convw<<<2048, 256, 0, stream>>>(conv1_w, wpack1);
  k_pack_convw<<<2048, 256, 0, stream>>>(conv2_w, wpack2);
  k_pack_wihx<<<2048, 256, 0, stream>>>(w_ih, wihx);
  k_pack_gru<<<2048, 256, 0, stream>>>(w_ih, w_hh, b_hh, Wp);
  k_pack_bf16<<<2048, 256, 0, stream>>>(mdn_mu_w, mdnmu, (long)KMIX * DD2 * DD2);
  k_pack_bf16<<<2048, 256, 0, stream>>>(mdn_sig_w, mdnsg, (long)KMIX * DD2 * DD2);
  k_init_hbuf<<<64, 256, 0, stream>>>(hbuf, flags);

  // --- conv block 1: y = conv(xpad1) + b ; LN+ReLU -> xpad2 ---
  gemm128<0, 1><<<dim3(4, 64), 256, 0, stream>>>(xpad1, DD, DD, wpack1, DD, (long)DD * DD, 9, DD,
                                                 ybuf, DD, conv1_b);
  ln_relu<1><<<BB * LL, 256, 0, stream>>>(ybuf, ln1_g, ln1_b, xpad2);

  // --- conv block 2 -> x2 (GRU input, plain bf16 [8192,512]) ---
  gemm128<0, 1><<<dim3(4, 64), 256, 0, stream>>>(xpad2, DD, DD, wpack2, DD, (long)DD * DD, 9, DD,
                                                 ybuf, DD, conv2_b);
  ln_relu<0><<<BB * LL, 256, 0, stream>>>(ybuf, ln2_g, ln2_b, x2);

  // --- gi_x = x2 @ w_ih[:, :512]^T + b_ih  (bf16 out, [8192, 3072]) ---
  gemm128<1, 0><<<dim3(24, 64), 256, 0, stream>>>(x2, DD, 0, wihx, DD, 0, 1, DD,
                                                  gix, 3 * DD2, b_ih);

  // --- persistent GRU scan (single dispatch, 511 internal flag barriers) ---
  gru_scan<<<64, 256, 0, stream>>>(Wp, gix, b_hh, hbuf, hseq, flags);

  // --- MDN heads ---
  gemm128<3, 0><<<dim3(64, 64), 256, 0, stream>>>(hseq, DD2, 0, mdnsg, DD2, 0, 1, DD2,
                                                  out + sigma_off, KMIX * DD2, mdn_sig_b);
  gemm128<2, 0><<<dim3(64, 64), 256, 0, stream>>>(hseq, DD2, 0, mdnmu, DD2, 0, 1, DD2,
                                                  out + mu_off, KMIX * DD2, mdn_mu_b);
  w_head<<<BB * LL / 4, 256, 0, stream>>>(hseq, mdn_w_w, mdn_w_b, out);
}